// Round 9
// baseline (5693.763 us; speedup 1.0000x reference)
//
#include <hip/hip_runtime.h>
#include <hip/hip_bf16.h>
#include <cstdio>
#include <cstdint>

#define BATCH 32
#define SEQ 512
#define BSQ (BATCH*SEQ)      // 16384
#define HIDD 300
#define HD 64
#define NHEAD 8
#define DHEAD 8
#define NLAYERS 6
#define FFD 1200
#define NCLS 1000

// ---------------- embedding + positional encoding -> acc = 2*emb + pos ------
__global__ void t9_embed(const int* __restrict__ toks,
                         const float* __restrict__ emb,
                         float* __restrict__ acc){
  int idx = blockIdx.x*256 + threadIdx.x;
  if (idx >= BSQ*HIDD) return;
  int row = idx / HIDD;
  int j   = idx - row*HIDD;
  int t = toks[row];
  float e = emb[(size_t)t*HIDD + j];
  int s = row & (SEQ-1);
  float expo = (float)(j & ~1) * (1.0f/(float)HIDD);
  float ang  = (float)s * expf(-expo * 9.210340371976184f); // pos * 10000^-expo
  float pe   = (j & 1) ? cosf(ang) : sinf(ang);
  acc[idx] = 2.0f*e + pe;                     // acc = x2 + x1 = 2*x1 + pos
}

// ---------------- generic fp32 GEMM:  C[M,N] = A[M,K] @ W[K,N] --------------
#define GBM 64
#define GBN 64
#define GBK 16
__global__ __launch_bounds__(256) void t9_gemm(
                 const float* __restrict__ A, const float* __restrict__ W,
                 const float* __restrict__ bias, float* __restrict__ C,
                 int M, int N, int K, int relu){
  __shared__ float sA[GBM][GBK+1];
  __shared__ float sW[GBK][GBN];
  int tid = threadIdx.x;
  int tx = tid & 15, ty = tid >> 4;
  int m0 = blockIdx.y * GBM, n0 = blockIdx.x * GBN;
  float cacc[4][4] = {};
  int lr = tid >> 4, lk = tid & 15;     // A-load mapping
  int lc = tid & 63, lkb = tid >> 6;    // W-load mapping
  for (int k0 = 0; k0 < K; k0 += GBK){
    for (int t = 0; t < 4; t++){
      int row = lr + t*16;
      float vv = 0.f;
      int gm = m0 + row, gk = k0 + lk;
      if (gm < M && gk < K) vv = A[(size_t)gm*K + gk];
      sA[row][lk] = vv;
    }
    for (int t = 0; t < 4; t++){
      int kk = lkb + t*4;
      float vv = 0.f;
      int gk = k0 + kk, gn = n0 + lc;
      if (gk < K && gn < N) vv = W[(size_t)gk*N + gn];
      sW[kk][lc] = vv;
    }
    __syncthreads();
    for (int kk = 0; kk < GBK; kk++){
      float a0[4], b0[4];
      for (int i=0;i<4;i++) a0[i] = sA[ty*4+i][kk];
      for (int j=0;j<4;j++) b0[j] = sW[kk][tx*4+j];
      for (int i=0;i<4;i++)
        for (int j=0;j<4;j++)
          cacc[i][j] = fmaf(a0[i], b0[j], cacc[i][j]);
    }
    __syncthreads();
  }
  for (int i=0;i<4;i++){
    int m = m0 + ty*4 + i;
    if (m >= M) continue;
    for (int j=0;j<4;j++){
      int n = n0 + tx*4 + j;
      if (n >= N) continue;
      float cv = cacc[i][j];
      if (bias) cv += bias[n];
      if (relu) cv = fmaxf(cv, 0.f);
      C[(size_t)m*N + n] = cv;
    }
  }
}

// ---------------- attention: one block per (b,h), K/V/Q staged in LDS -------
__global__ __launch_bounds__(256) void t9_attn(
                 const float* __restrict__ qg, const float* __restrict__ kg,
                 const float* __restrict__ vg, const int* __restrict__ toks,
                 float* __restrict__ aout){
  __shared__ float kb[SEQ][DHEAD+1];
  __shared__ float vb[SEQ][DHEAD+1];
  __shared__ float qb[SEQ][DHEAD+1];
  __shared__ float msk[SEQ];
  int bh = blockIdx.x;
  int b = bh >> 3, h = bh & 7;
  int tid = threadIdx.x;
  for (int idx = tid; idx < SEQ*DHEAD; idx += 256){
    int s = idx >> 3, d = idx & 7;
    size_t g = (size_t)(b*SEQ+s)*HD + d*NHEAD + h;  // interleaved head layout
    kb[s][d] = kg[g];
    vb[s][d] = vg[g];
    qb[s][d] = qg[g];
  }
  for (int s = tid; s < SEQ; s += 256) msk[s] = (toks[b*SEQ+s]==0) ? 1.f : 0.f;
  __syncthreads();
  const float scale = 0.057735026918962574f;  // 1/sqrt(300)
  int lane = tid & 63, w = tid >> 6;
  for (int qi = w; qi < SEQ; qi += 4){
    float qv[DHEAD];
    for (int d=0; d<DHEAD; d++) qv[d] = qb[qi][d];
    float e[8]; float mx = -1e30f;
    for (int j=0;j<8;j++){
      int kk = lane + 64*j;
      float sc = 0.f;
      for (int d=0; d<DHEAD; d++) sc += qv[d]*kb[kk][d];
      sc *= scale;
      if (msk[kk] > 0.5f) sc = -1e9f;   // replacement semantics
      e[j] = sc; mx = fmaxf(mx, sc);
    }
    for (int off=32; off; off>>=1) mx = fmaxf(mx, __shfl_xor(mx, off));
    float p[8], sum = 0.f;
    for (int j=0;j<8;j++){ p[j] = __expf(e[j]-mx); sum += p[j]; }
    for (int off=32; off; off>>=1) sum += __shfl_xor(sum, off);
    float inv = 1.f/sum;
    float o[DHEAD] = {};
    for (int j=0;j<8;j++){
      int kk = lane + 64*j; float pj = p[j];
      for (int d=0; d<DHEAD; d++) o[d] += pj * vb[kk][d];
    }
    for (int d=0; d<DHEAD; d++)
      for (int off=32; off; off>>=1) o[d] += __shfl_xor(o[d], off);
    if (lane == 0){
      size_t base = (size_t)(b*SEQ+qi)*HD + h*DHEAD;  // head-major output
      for (int d=0; d<DHEAD; d++) aout[base+d] = o[d]*inv;
    }
  }
}

// ---------------- fused residual add + LayerNorm (ddof=1), optional acc+= ---
__global__ __launch_bounds__(256) void t9_addnorm(
                 const float* __restrict__ xa, const float* __restrict__ xb,
                 float* __restrict__ y, float* __restrict__ accum,
                 const float* __restrict__ gamma, const float* __restrict__ beta,
                 int l){
  __shared__ float red[8];
  int row = blockIdx.x, tid = threadIdx.x;
  size_t base = (size_t)row*HIDD;
  float v0 = xa[base+tid] + xb[base+tid];
  float v1 = 0.f;
  int has1 = (tid+256 < HIDD);
  if (has1) v1 = xa[base+tid+256] + xb[base+tid+256];
  float s = v0+v1, sq = v0*v0+v1*v1;
  for (int off=32; off; off>>=1){ s += __shfl_down(s,off); sq += __shfl_down(sq,off); }
  int lane = tid & 63, w = tid >> 6;
  if (lane==0){ red[w]=s; red[4+w]=sq; }
  __syncthreads();
  float sum = red[0]+red[1]+red[2]+red[3];
  float ssq = red[4]+red[5]+red[6]+red[7];
  float mu  = sum * (1.0f/HIDD);
  float var = (ssq - (float)HIDD*mu*mu) * (1.0f/(HIDD-1));
  float rstd = rsqrtf(var + 1e-8f);
  float g = gamma[l], be = beta[l];
  float o0 = g*(v0-mu)*rstd + be;
  y[base+tid] = o0;
  if (accum) accum[base+tid] += o0;
  if (has1){
    float o1 = g*(v1-mu)*rstd + be;
    y[base+tid+256] = o1;
    if (accum) accum[base+tid+256] += o1;
  }
}

// ---------------- sum over sequence: (B,S,HID) -> (B,HID) -------------------
__global__ void t9_colsum(const float* __restrict__ outb, float* __restrict__ sums){
  int b = blockIdx.x, j = threadIdx.x;
  if (j >= HIDD) return;
  float s = 0.f;
  size_t base = (size_t)b*SEQ*HIDD;
  for (int t=0; t<SEQ; t++) s += outb[base + (size_t)t*HIDD + j];
  sums[b*HIDD + j] = s;
}

// ---------------- classifier head: LayerNorm(ddof=1) + softmax -> fp32 -----
__device__ __forceinline__ float t9_bsum(float val, float* red){
  for (int off=32; off; off>>=1) val += __shfl_down(val, off);
  __syncthreads();
  if ((threadIdx.x & 63)==0) red[threadIdx.x>>6] = val;
  __syncthreads();
  return red[0]+red[1]+red[2]+red[3];
}
__device__ __forceinline__ float t9_bmax(float val, float* red){
  for (int off=32; off; off>>=1) val = fmaxf(val, __shfl_down(val, off));
  __syncthreads();
  if ((threadIdx.x & 63)==0) red[threadIdx.x>>6] = val;
  __syncthreads();
  return fmaxf(fmaxf(red[0],red[1]), fmaxf(red[2],red[3]));
}

__global__ __launch_bounds__(256) void t9_final(
                  const float* __restrict__ logits,
                  const float* __restrict__ gf, const float* __restrict__ bff,
                  float* __restrict__ outp){   // <-- FP32 OUTPUT (the fix)
  __shared__ float red[4];
  int b = blockIdx.x, tid = threadIdx.x;
  size_t base = (size_t)b*NCLS;
  float v[4];
  float s = 0.f, sq = 0.f;
  for (int t=0;t<4;t++){
    int j = tid + t*256;
    float x = (j < NCLS) ? logits[base+j] : 0.f;
    v[t] = x; s += x; sq += x*x;
  }
  s  = t9_bsum(s, red);
  sq = t9_bsum(sq, red);
  float mu  = s * (1.0f/NCLS);
  float var = (sq - (float)NCLS*mu*mu) * (1.0f/(NCLS-1));
  float rstd = rsqrtf(var + 1e-8f);
  float g = gf[0], be = bff[0];
  float y[4]; float mx = -1e30f;
  for (int t=0;t<4;t++){
    int j = tid + t*256;
    y[t] = g*(v[t]-mu)*rstd + be;
    if (j < NCLS) mx = fmaxf(mx, y[t]);
  }
  mx = t9_bmax(mx, red);
  float p[4]; float es = 0.f;
  for (int t=0;t<4;t++){
    int j = tid + t*256;
    p[t] = (j < NCLS) ? __expf(y[t]-mx) : 0.f;
    es += p[t];
  }
  es = t9_bsum(es, red);
  float inv = 1.0f/es;
  for (int t=0;t<4;t++){
    int j = tid + t*256;
    if (j < NCLS) outp[base+j] = p[t]*inv;
  }
}

// ---------------------------------------------------------------------------
extern "C" void kernel_launch(void* const* d_in, const int* in_sizes, int n_in,
                              void* d_out, int out_size, void* d_ws, size_t ws_size,
                              hipStream_t stream){
  const int*   toks = (const int*)d_in[0];
  const float* emb  = (const float*)d_in[1];
  const float* WQ   = (const float*)d_in[2];
  const float* WK   = (const float*)d_in[3];
  const float* WV   = (const float*)d_in[4];
  const float* WO   = (const float*)d_in[5];
  const float* W1   = (const float*)d_in[6];
  const float* b1   = (const float*)d_in[7];
  const float* W2   = (const float*)d_in[8];
  const float* b2   = (const float*)d_in[9];
  const float* g1   = (const float*)d_in[10];
  const float* be1  = (const float*)d_in[11];
  const float* g2   = (const float*)d_in[12];
  const float* be2  = (const float*)d_in[13];
  const float* Vd   = (const float*)d_in[14];
  const float* gf   = (const float*)d_in[15];
  const float* bff  = (const float*)d_in[16];
  float* outp = (float*)d_out;                      // FP32 output buffer

  float* acc  = (float*)d_ws;                       // (BSQ,HID) running residual sum
  float* xn   = acc  + (size_t)BSQ*HIDD;            // (BSQ,HID) post-LN1
  float* outb = xn   + (size_t)BSQ*HIDD;            // (BSQ,HID) encoder output
  float* tmp  = outb + (size_t)BSQ*HIDD;            // (BSQ,HID) attnout / ff2
  float* big  = tmp  + (size_t)BSQ*HIDD;            // q,k,v,a then ff1
  float* q    = big;
  float* k    = big + (size_t)BSQ*HD;
  float* v    = big + 2*(size_t)BSQ*HD;
  float* aat  = big + 3*(size_t)BSQ*HD;
  float* ff1  = big;                                // reuse (q/k/v/a dead by then)
  float* sums   = big + (size_t)BSQ*FFD;            // (B,HID)
  float* logits = sums + BATCH*HIDD;                // (B,NCLS)

  t9_embed<<<(BSQ*HIDD+255)/256, 256, 0, stream>>>(toks, emb, acc);

  for (int l = 0; l < NLAYERS; l++){
    t9_gemm<<<dim3(1, BSQ/GBM),256,0,stream>>>(acc, WQ + (size_t)l*HIDD*HD, nullptr, q, BSQ, HD, HIDD, 0);
    t9_gemm<<<dim3(1, BSQ/GBM),256,0,stream>>>(acc, WK + (size_t)l*HIDD*HD, nullptr, k, BSQ, HD, HIDD, 0);
    t9_gemm<<<dim3(1, BSQ/GBM),256,0,stream>>>(acc, WV + (size_t)l*HIDD*HD, nullptr, v, BSQ, HD, HIDD, 0);
    t9_attn<<<BATCH*NHEAD, 256, 0, stream>>>(q, k, v, toks, aat);
    t9_gemm<<<dim3((HIDD+GBN-1)/GBN, BSQ/GBM),256,0,stream>>>(aat, WO + (size_t)l*HD*HIDD, nullptr, tmp, BSQ, HIDD, HD, 0);
    t9_addnorm<<<BSQ,256,0,stream>>>(tmp, acc, xn, nullptr, g1, be1, l);
    t9_gemm<<<dim3((FFD+GBN-1)/GBN, BSQ/GBM),256,0,stream>>>(xn, W1 + (size_t)l*HIDD*FFD, b1 + (size_t)l*FFD, ff1, BSQ, FFD, HIDD, 1);
    t9_gemm<<<dim3((HIDD+GBN-1)/GBN, BSQ/GBM),256,0,stream>>>(ff1, W2 + (size_t)l*FFD*HIDD, b2 + (size_t)l*HIDD, tmp, BSQ, HIDD, FFD, 0);
    t9_addnorm<<<BSQ,256,0,stream>>>(tmp, xn, outb, acc, g2, be2, l);
  }

  t9_colsum<<<BATCH, 320, 0, stream>>>(outb, sums);
  t9_gemm<<<dim3((NCLS+GBN-1)/GBN, 1),256,0,stream>>>(sums, Vd, nullptr, logits, BATCH, NCLS, HIDD, 0);
  t9_final<<<BATCH, 256, 0, stream>>>(logits, gf, bff, outp);

  // -------- diagnostics (skipped under graph capture) --------
  hipStreamCaptureStatus cs = hipStreamCaptureStatusNone;
  hipStreamIsCapturing(stream, &cs);
  if (cs == hipStreamCaptureStatusNone){
    hipError_t e_sync = hipStreamSynchronize(stream);
    float ho[4] = {-1,-1,-1,-1};
    hipMemcpy(ho, d_out, 16, hipMemcpyDeviceToHost);
    void* ob = nullptr; size_t orng = 0;
    hipMemGetAddressRange((hipDeviceptr_t*)&ob, &orng, (hipDeviceptr_t)(uintptr_t)d_out);
    fprintf(stderr, "[t9] sync=%s d_out_range=%zu out[0..3]=%g,%g,%g,%g\n",
            hipGetErrorString(e_sync), orng, ho[0], ho[1], ho[2], ho[3]);
    fflush(stderr);
  }
}

// Round 10
// 2459.019 us; speedup vs baseline: 2.3155x; 2.3155x over previous
//
#include <hip/hip_runtime.h>
#include <hip/hip_bf16.h>
#include <cstdio>
#include <cstdint>

#define BATCH 32
#define SEQ 512
#define BSQ (BATCH*SEQ)      // 16384
#define HIDD 300
#define HD 64
#define NHEAD 8
#define DHEAD 8
#define NLAYERS 6
#define FFD 1200
#define NCLS 1000

typedef short short8 __attribute__((ext_vector_type(8)));
typedef float floatx4 __attribute__((ext_vector_type(4)));

__device__ __forceinline__ short f2b(float v){
  __hip_bfloat16 h = __float2bfloat16(v);
  short s; __builtin_memcpy(&s, &h, 2); return s;
}

// ---------------- embedding + positional encoding -> acc = 2*emb + pos ------
__global__ void t10_embed(const int* __restrict__ toks,
                          const float* __restrict__ emb,
                          float* __restrict__ acc){
  int idx = blockIdx.x*256 + threadIdx.x;
  if (idx >= BSQ*HIDD) return;
  int row = idx / HIDD;
  int j   = idx - row*HIDD;
  int t = toks[row];
  float e = emb[(size_t)t*HIDD + j];
  int s = row & (SEQ-1);
  float expo = (float)(j & ~1) * (1.0f/(float)HIDD);
  float ang  = (float)s * expf(-expo * 9.210340371976184f);
  float pe   = (j & 1) ? cosf(ang) : sinf(ang);
  acc[idx] = 2.0f*e + pe;
}

// ---------------- weight prep: fp32 [K][N] -> bf16 transposed [Npad][Kpad] --
__global__ void prep_w(const float* __restrict__ src, short* __restrict__ dst,
                       int K, int N, int Kpad, int rows, int nbase,
                       int sls, int dls, int total){
  int idx = blockIdx.x*256 + threadIdx.x;
  if (idx >= total) return;
  int l   = idx / (rows*Kpad);
  int rem = idx - l*(rows*Kpad);
  int n = rem / Kpad;
  int k = rem - n*Kpad;
  float v = (n < N && k < K) ? src[(size_t)l*sls + (size_t)k*N + n] : 0.f;
  dst[(size_t)l*dls + (size_t)(nbase+n)*Kpad + k] = f2b(v);
}

// ---------------- bf16 MFMA GEMM: C[M,N] = A[M,K](fp32) @ W[K,N] ------------
// Wt is pre-transposed bf16 [Npad][Kpad], zero-padded. 64x64 tile, 4 waves.
__global__ __launch_bounds__(256) void mm_bf16(
    const float* __restrict__ A, const short* __restrict__ Wt,
    const float* __restrict__ bias, float* __restrict__ C,
    int M, int N, int K, int Kpad, int relu){
  __shared__ short sA[64][40];   // +8 pad: 80B row stride, 16B aligned frags
  __shared__ short sB[64][40];
  int tid = threadIdx.x;
  int m0 = blockIdx.y*64, n0 = blockIdx.x*64;
  int lane = tid & 63, wv = tid >> 6;
  int wm = (wv & 1)*32, wn = (wv >> 1)*32;
  int l15 = lane & 15, quad = lane >> 4;
  floatx4 acc[2][2] = {};
  int srow = tid >> 2, sko = (tid & 3)*8;
  const float* Arow = A  + (size_t)(m0 + srow)*K;
  const short* Brow = Wt + (size_t)(n0 + srow)*Kpad;
  int nch = Kpad >> 5;
  for (int c = 0; c < nch; c++){
    int k0 = c*32;
    __syncthreads();
    {  // stage A tile (fp32 -> bf16)
      int gk = k0 + sko;
      short8 v;
      if (gk + 8 <= K){
        const float4* p = (const float4*)(Arow + gk);
        float4 x = p[0], y = p[1];
        v[0]=f2b(x.x); v[1]=f2b(x.y); v[2]=f2b(x.z); v[3]=f2b(x.w);
        v[4]=f2b(y.x); v[5]=f2b(y.y); v[6]=f2b(y.z); v[7]=f2b(y.w);
      } else {
        for (int j=0;j<8;j++){
          int kk = gk + j;
          v[j] = (kk < K) ? f2b(Arow[kk]) : (short)0;
        }
      }
      *(short8*)&sA[srow][sko] = v;
    }
    {  // stage B tile (already bf16 + padded: unconditional 16B load)
      *(short8*)&sB[srow][sko] = *(const short8*)(Brow + k0 + sko);
    }
    __syncthreads();
    short8 af[2], bf[2];
    for (int i=0;i<2;i++)
      af[i] = *(const short8*)&sA[wm + i*16 + l15][quad*8];
    for (int j=0;j<2;j++)
      bf[j] = *(const short8*)&sB[wn + j*16 + l15][quad*8];
    for (int i=0;i<2;i++)
      for (int j=0;j<2;j++)
        acc[i][j] = __builtin_amdgcn_mfma_f32_16x16x32_bf16(af[i], bf[j], acc[i][j], 0,0,0);
  }
  for (int j=0;j<2;j++){
    int n = n0 + wn + j*16 + l15;
    if (n >= N) continue;
    float bv = bias ? bias[n] : 0.f;
    for (int i=0;i<2;i++){
      int mbase = m0 + wm + i*16 + quad*4;
      for (int r=0;r<4;r++){
        float cv = acc[i][j][r] + bv;
        if (relu) cv = fmaxf(cv, 0.f);
        C[(size_t)(mbase+r)*N + n] = cv;
      }
    }
  }
}

// ---------------- attention on packed qkv [BSQ][192] ------------------------
__global__ __launch_bounds__(256) void t10_attn(
                 const float* __restrict__ qkv, const int* __restrict__ toks,
                 float* __restrict__ aout){
  __shared__ float kb[SEQ][DHEAD+1];
  __shared__ float vb[SEQ][DHEAD+1];
  __shared__ float qb[SEQ][DHEAD+1];
  __shared__ float msk[SEQ];
  int bh = blockIdx.x;
  int b = bh >> 3, h = bh & 7;
  int tid = threadIdx.x;
  for (int idx = tid; idx < SEQ*DHEAD; idx += 256){
    int s = idx >> 3, d = idx & 7;
    size_t g = (size_t)(b*SEQ+s)*192 + d*NHEAD + h;  // interleaved head layout
    qb[s][d] = qkv[g];
    kb[s][d] = qkv[g + 64];
    vb[s][d] = qkv[g + 128];
  }
  for (int s = tid; s < SEQ; s += 256) msk[s] = (toks[b*SEQ+s]==0) ? 1.f : 0.f;
  __syncthreads();
  const float scale = 0.057735026918962574f;  // 1/sqrt(300)
  int lane = tid & 63, w = tid >> 6;
  for (int qi = w; qi < SEQ; qi += 4){
    float qv[DHEAD];
    for (int d=0; d<DHEAD; d++) qv[d] = qb[qi][d];
    float e[8]; float mx = -1e30f;
    for (int j=0;j<8;j++){
      int kk = lane + 64*j;
      float sc = 0.f;
      for (int d=0; d<DHEAD; d++) sc += qv[d]*kb[kk][d];
      sc *= scale;
      if (msk[kk] > 0.5f) sc = -1e9f;
      e[j] = sc; mx = fmaxf(mx, sc);
    }
    for (int off=32; off; off>>=1) mx = fmaxf(mx, __shfl_xor(mx, off));
    float p[8], sum = 0.f;
    for (int j=0;j<8;j++){ p[j] = __expf(e[j]-mx); sum += p[j]; }
    for (int off=32; off; off>>=1) sum += __shfl_xor(sum, off);
    float inv = 1.f/sum;
    float o[DHEAD] = {};
    for (int j=0;j<8;j++){
      int kk = lane + 64*j; float pj = p[j];
      for (int d=0; d<DHEAD; d++) o[d] += pj * vb[kk][d];
    }
    for (int d=0; d<DHEAD; d++)
      for (int off=32; off; off>>=1) o[d] += __shfl_xor(o[d], off);
    if (lane == 0){
      size_t base = (size_t)(b*SEQ+qi)*HD + h*DHEAD;  // head-major output
      for (int d=0; d<DHEAD; d++) aout[base+d] = o[d]*inv;
    }
  }
}

// ---------------- fused residual add + LayerNorm (ddof=1), optional acc+= ---
__global__ __launch_bounds__(256) void t10_addnorm(
                 const float* __restrict__ xa, const float* __restrict__ xb,
                 float* __restrict__ y, float* __restrict__ accum,
                 const float* __restrict__ gamma, const float* __restrict__ beta,
                 int l){
  __shared__ float red[8];
  int row = blockIdx.x, tid = threadIdx.x;
  size_t base = (size_t)row*HIDD;
  float v0 = xa[base+tid] + xb[base+tid];
  float v1 = 0.f;
  int has1 = (tid+256 < HIDD);
  if (has1) v1 = xa[base+tid+256] + xb[base+tid+256];
  float s = v0+v1, sq = v0*v0+v1*v1;
  for (int off=32; off; off>>=1){ s += __shfl_down(s,off); sq += __shfl_down(sq,off); }
  int lane = tid & 63, w = tid >> 6;
  if (lane==0){ red[w]=s; red[4+w]=sq; }
  __syncthreads();
  float sum = red[0]+red[1]+red[2]+red[3];
  float ssq = red[4]+red[5]+red[6]+red[7];
  float mu  = sum * (1.0f/HIDD);
  float var = (ssq - (float)HIDD*mu*mu) * (1.0f/(HIDD-1));
  float rstd = rsqrtf(var + 1e-8f);
  float g = gamma[l], be = beta[l];
  float o0 = g*(v0-mu)*rstd + be;
  y[base+tid] = o0;
  if (accum) accum[base+tid] += o0;
  if (has1){
    float o1 = g*(v1-mu)*rstd + be;
    y[base+tid+256] = o1;
    if (accum) accum[base+tid+256] += o1;
  }
}

// ---------------- fp32 tiled GEMM (classifier only, M=32) -------------------
#define GBM 64
#define GBN 64
#define GBK 16
__global__ __launch_bounds__(256) void t9_gemm(
                 const float* __restrict__ A, const float* __restrict__ W,
                 const float* __restrict__ bias, float* __restrict__ C,
                 int M, int N, int K, int relu){
  __shared__ float sA[GBM][GBK+1];
  __shared__ float sW[GBK][GBN];
  int tid = threadIdx.x;
  int tx = tid & 15, ty = tid >> 4;
  int m0 = blockIdx.y * GBM, n0 = blockIdx.x * GBN;
  float cacc[4][4] = {};
  int lr = tid >> 4, lk = tid & 15;
  int lc = tid & 63, lkb = tid >> 6;
  for (int k0 = 0; k0 < K; k0 += GBK){
    for (int t = 0; t < 4; t++){
      int row = lr + t*16;
      float vv = 0.f;
      int gm = m0 + row, gk = k0 + lk;
      if (gm < M && gk < K) vv = A[(size_t)gm*K + gk];
      sA[row][lk] = vv;
    }
    for (int t = 0; t < 4; t++){
      int kk = lkb + t*4;
      float vv = 0.f;
      int gk = k0 + kk, gn = n0 + lc;
      if (gk < K && gn < N) vv = W[(size_t)gk*N + gn];
      sW[kk][lc] = vv;
    }
    __syncthreads();
    for (int kk = 0; kk < GBK; kk++){
      float a0[4], b0[4];
      for (int i=0;i<4;i++) a0[i] = sA[ty*4+i][kk];
      for (int j=0;j<4;j++) b0[j] = sW[kk][tx*4+j];
      for (int i=0;i<4;i++)
        for (int j=0;j<4;j++)
          cacc[i][j] = fmaf(a0[i], b0[j], cacc[i][j]);
    }
    __syncthreads();
  }
  for (int i=0;i<4;i++){
    int m = m0 + ty*4 + i;
    if (m >= M) continue;
    for (int j=0;j<4;j++){
      int n = n0 + tx*4 + j;
      if (n >= N) continue;
      float cv = cacc[i][j];
      if (bias) cv += bias[n];
      if (relu) cv = fmaxf(cv, 0.f);
      C[(size_t)m*N + n] = cv;
    }
  }
}

// ---------------- sum over sequence: (B,S,HID) -> (B,HID) -------------------
__global__ void t10_colsum(const float* __restrict__ outb, float* __restrict__ sums){
  int b = blockIdx.x, j = threadIdx.x;
  if (j >= HIDD) return;
  float s = 0.f;
  size_t base = (size_t)b*SEQ*HIDD;
  for (int t=0; t<SEQ; t++) s += outb[base + (size_t)t*HIDD + j];
  sums[b*HIDD + j] = s;
}

// ---------------- classifier head: LayerNorm(ddof=1) + softmax -> fp32 -----
__device__ __forceinline__ float t10_bsum(float val, float* red){
  for (int off=32; off; off>>=1) val += __shfl_down(val, off);
  __syncthreads();
  if ((threadIdx.x & 63)==0) red[threadIdx.x>>6] = val;
  __syncthreads();
  return red[0]+red[1]+red[2]+red[3];
}
__device__ __forceinline__ float t10_bmax(float val, float* red){
  for (int off=32; off; off>>=1) val = fmaxf(val, __shfl_down(val, off));
  __syncthreads();
  if ((threadIdx.x & 63)==0) red[threadIdx.x>>6] = val;
  __syncthreads();
  return fmaxf(fmaxf(red[0],red[1]), fmaxf(red[2],red[3]));
}

__global__ __launch_bounds__(256) void t10_final(
                  const float* __restrict__ logits,
                  const float* __restrict__ gf, const float* __restrict__ bff,
                  float* __restrict__ outp){
  __shared__ float red[4];
  int b = blockIdx.x, tid = threadIdx.x;
  size_t base = (size_t)b*NCLS;
  float v[4];
  float s = 0.f, sq = 0.f;
  for (int t=0;t<4;t++){
    int j = tid + t*256;
    float x = (j < NCLS) ? logits[base+j] : 0.f;
    v[t] = x; s += x; sq += x*x;
  }
  s  = t10_bsum(s, red);
  sq = t10_bsum(sq, red);
  float mu  = s * (1.0f/NCLS);
  float var = (sq - (float)NCLS*mu*mu) * (1.0f/(NCLS-1));
  float rstd = rsqrtf(var + 1e-8f);
  float g = gf[0], be = bff[0];
  float y[4]; float mx = -1e30f;
  for (int t=0;t<4;t++){
    int j = tid + t*256;
    y[t] = g*(v[t]-mu)*rstd + be;
    if (j < NCLS) mx = fmaxf(mx, y[t]);
  }
  mx = t10_bmax(mx, red);
  float p[4]; float es = 0.f;
  for (int t=0;t<4;t++){
    int j = tid + t*256;
    p[t] = (j < NCLS) ? __expf(y[t]-mx) : 0.f;
    es += p[t];
  }
  es = t10_bsum(es, red);
  float inv = 1.0f/es;
  for (int t=0;t<4;t++){
    int j = tid + t*256;
    if (j < NCLS) outp[base+j] = p[t]*inv;
  }
}

// ---------------------------------------------------------------------------
extern "C" void kernel_launch(void* const* d_in, const int* in_sizes, int n_in,
                              void* d_out, int out_size, void* d_ws, size_t ws_size,
                              hipStream_t stream){
  const int*   toks = (const int*)d_in[0];
  const float* emb  = (const float*)d_in[1];
  const float* WQ   = (const float*)d_in[2];
  const float* WK   = (const float*)d_in[3];
  const float* WV   = (const float*)d_in[4];
  const float* WO   = (const float*)d_in[5];
  const float* W1   = (const float*)d_in[6];
  const float* b1   = (const float*)d_in[7];
  const float* W2   = (const float*)d_in[8];
  const float* b2   = (const float*)d_in[9];
  const float* g1   = (const float*)d_in[10];
  const float* be1  = (const float*)d_in[11];
  const float* g2   = (const float*)d_in[12];
  const float* be2  = (const float*)d_in[13];
  const float* Vd   = (const float*)d_in[14];
  const float* gf   = (const float*)d_in[15];
  const float* bff  = (const float*)d_in[16];
  float* outp = (float*)d_out;

  // float workspace
  float* acc  = (float*)d_ws;
  float* xn   = acc  + (size_t)BSQ*HIDD;
  float* outb = xn   + (size_t)BSQ*HIDD;
  float* tmp  = outb + (size_t)BSQ*HIDD;
  float* big  = tmp  + (size_t)BSQ*HIDD;            // 19.66M floats
  float* qkv  = big;                                // (BSQ,192)
  float* aat  = big + (size_t)BSQ*192;              // (BSQ,64)
  float* ff1  = big;                                // (BSQ,1200) reuse
  float* sums   = big + (size_t)BSQ*FFD;
  float* logits = sums + BATCH*HIDD;
  // bf16 weight workspace (transposed, padded)
  short* wt   = (short*)(logits + BATCH*NCLS);
  short* wqkv = wt;                                  // [6][192][320]
  short* wo   = wqkv + (size_t)6*192*320;            // [6][320][64]
  short* w1t  = wo   + (size_t)6*320*64;             // [6][1216][320]
  short* w2t  = w1t  + (size_t)6*1216*320;           // [6][320][1216]

  // ---- weight prep (runs every launch; ~5M elems) ----
  {
    int tq = 6*64*320;
    prep_w<<<(tq+255)/256,256,0,stream>>>(WQ, wqkv, 300, 64, 320, 64, 0,   19200, 61440, tq);
    prep_w<<<(tq+255)/256,256,0,stream>>>(WK, wqkv, 300, 64, 320, 64, 64,  19200, 61440, tq);
    prep_w<<<(tq+255)/256,256,0,stream>>>(WV, wqkv, 300, 64, 320, 64, 128, 19200, 61440, tq);
    int to = 6*320*64;
    prep_w<<<(to+255)/256,256,0,stream>>>(WO, wo, 64, 300, 64, 320, 0, 19200, 20480, to);
    int t1 = 6*1216*320;
    prep_w<<<(t1+255)/256,256,0,stream>>>(W1, w1t, 300, 1200, 320, 1216, 0, 360000, 389120, t1);
    int t2 = 6*320*1216;
    prep_w<<<(t2+255)/256,256,0,stream>>>(W2, w2t, 1200, 300, 1216, 320, 0, 360000, 389120, t2);
  }

  t10_embed<<<(BSQ*HIDD+255)/256, 256, 0, stream>>>(toks, emb, acc);

  for (int l = 0; l < NLAYERS; l++){
    mm_bf16<<<dim3(3,256),256,0,stream>>>(acc, wqkv + (size_t)l*61440, nullptr, qkv,
                                          BSQ, 192, 300, 320, 0);
    t10_attn<<<BATCH*NHEAD, 256, 0, stream>>>(qkv, toks, aat);
    mm_bf16<<<dim3(5,256),256,0,stream>>>(aat, wo + (size_t)l*20480, nullptr, tmp,
                                          BSQ, 300, 64, 64, 0);
    t10_addnorm<<<BSQ,256,0,stream>>>(tmp, acc, xn, nullptr, g1, be1, l);
    mm_bf16<<<dim3(19,256),256,0,stream>>>(xn, w1t + (size_t)l*389120, b1 + (size_t)l*FFD, ff1,
                                           BSQ, 1200, 300, 320, 1);
    mm_bf16<<<dim3(5,256),256,0,stream>>>(ff1, w2t + (size_t)l*389120, b2 + (size_t)l*HIDD, tmp,
                                          BSQ, 300, 1200, 1216, 0);
    t10_addnorm<<<BSQ,256,0,stream>>>(tmp, xn, outb, acc, g2, be2, l);
  }

  t10_colsum<<<BATCH, 320, 0, stream>>>(outb, sums);
  t9_gemm<<<dim3((NCLS+GBN-1)/GBN, 1),256,0,stream>>>(sums, Vd, nullptr, logits, BATCH, NCLS, HIDD, 0);
  t10_final<<<BATCH, 256, 0, stream>>>(logits, gf, bff, outp);

  // minimal capture-guarded diagnostic
  hipStreamCaptureStatus cs = hipStreamCaptureStatusNone;
  hipStreamIsCapturing(stream, &cs);
  if (cs == hipStreamCaptureStatusNone){
    hipError_t e_sync = hipStreamSynchronize(stream);
    float ho[4] = {-1,-1,-1,-1};
    hipMemcpy(ho, d_out, 16, hipMemcpyDeviceToHost);
    fprintf(stderr, "[t10] sync=%s out[0..3]=%g,%g,%g,%g\n",
            hipGetErrorString(e_sync), ho[0], ho[1], ho[2], ho[3]);
    fflush(stderr);
  }
}

// Round 11
// 1695.280 us; speedup vs baseline: 3.3586x; 1.4505x over previous
//
#include <hip/hip_runtime.h>
#include <hip/hip_bf16.h>
#include <cstdio>
#include <cstdint>

#define BATCH 32
#define SEQ 512
#define BSQ (BATCH*SEQ)      // 16384
#define HIDD 300
#define HD 64
#define NHEAD 8
#define DHEAD 8
#define NLAYERS 6
#define FFD 1200
#define NCLS 1000

typedef short short8 __attribute__((ext_vector_type(8)));
typedef float floatx4 __attribute__((ext_vector_type(4)));

__device__ __forceinline__ short f2b(float v){
  __hip_bfloat16 h = __float2bfloat16(v);
  short s; __builtin_memcpy(&s, &h, 2); return s;
}

// ---------------- embedding + positional encoding -> acc = 2*emb + pos ------
__global__ void t10_embed(const int* __restrict__ toks,
                          const float* __restrict__ emb,
                          float* __restrict__ acc){
  int idx = blockIdx.x*256 + threadIdx.x;
  if (idx >= BSQ*HIDD) return;
  int row = idx / HIDD;
  int j   = idx - row*HIDD;
  int t = toks[row];
  float e = emb[(size_t)t*HIDD + j];
  int s = row & (SEQ-1);
  float expo = (float)(j & ~1) * (1.0f/(float)HIDD);
  float ang  = (float)s * expf(-expo * 9.210340371976184f);
  float pe   = (j & 1) ? cosf(ang) : sinf(ang);
  acc[idx] = 2.0f*e + pe;
}

// ------- weight prep: fp32 [K][N] -> bf16 transposed [Npad][Kpad] -----------
// perm: dest col n takes source col (n&7)*8 + (n>>3)  (head-major reorder)
__global__ void prep_w(const float* __restrict__ src, short* __restrict__ dst,
                       int K, int N, int Kpad, int rows, int nbase,
                       int sls, int dls, int total, int perm){
  int idx = blockIdx.x*256 + threadIdx.x;
  if (idx >= total) return;
  int l   = idx / (rows*Kpad);
  int rem = idx - l*(rows*Kpad);
  int n = rem / Kpad;
  int k = rem - n*Kpad;
  int sc = perm ? ((n & 7)*8 + (n >> 3)) : n;
  float v = (n < N && k < K) ? src[(size_t)l*sls + (size_t)k*N + sc] : 0.f;
  dst[(size_t)l*dls + (size_t)(nbase+n)*Kpad + k] = f2b(v);
}

// ---------------- bf16 MFMA GEMM: C[M,N] = A[M,K](fp32) @ W[K,N] ------------
__global__ __launch_bounds__(256) void mm_bf16(
    const float* __restrict__ A, const short* __restrict__ Wt,
    const float* __restrict__ bias, float* __restrict__ C,
    int M, int N, int K, int Kpad, int relu){
  __shared__ short sA[64][40];
  __shared__ short sB[64][40];
  int tid = threadIdx.x;
  int m0 = blockIdx.y*64, n0 = blockIdx.x*64;
  int lane = tid & 63, wv = tid >> 6;
  int wm = (wv & 1)*32, wn = (wv >> 1)*32;
  int l15 = lane & 15, quad = lane >> 4;
  floatx4 acc[2][2] = {};
  int srow = tid >> 2, sko = (tid & 3)*8;
  const float* Arow = A  + (size_t)(m0 + srow)*K;
  const short* Brow = Wt + (size_t)(n0 + srow)*Kpad;
  int nch = Kpad >> 5;
  for (int c = 0; c < nch; c++){
    int k0 = c*32;
    __syncthreads();
    {
      int gk = k0 + sko;
      short8 v;
      if (gk + 8 <= K){
        const float4* p = (const float4*)(Arow + gk);
        float4 x = p[0], y = p[1];
        v[0]=f2b(x.x); v[1]=f2b(x.y); v[2]=f2b(x.z); v[3]=f2b(x.w);
        v[4]=f2b(y.x); v[5]=f2b(y.y); v[6]=f2b(y.z); v[7]=f2b(y.w);
      } else {
        for (int j=0;j<8;j++){
          int kk = gk + j;
          v[j] = (kk < K) ? f2b(Arow[kk]) : (short)0;
        }
      }
      *(short8*)&sA[srow][sko] = v;
    }
    {
      *(short8*)&sB[srow][sko] = *(const short8*)(Brow + k0 + sko);
    }
    __syncthreads();
    short8 af[2], bf[2];
    for (int i=0;i<2;i++)
      af[i] = *(const short8*)&sA[wm + i*16 + l15][quad*8];
    for (int j=0;j<2;j++)
      bf[j] = *(const short8*)&sB[wn + j*16 + l15][quad*8];
    for (int i=0;i<2;i++)
      for (int j=0;j<2;j++)
        acc[i][j] = __builtin_amdgcn_mfma_f32_16x16x32_bf16(af[i], bf[j], acc[i][j], 0,0,0);
  }
  for (int j=0;j<2;j++){
    int n = n0 + wn + j*16 + l15;
    if (n >= N) continue;
    float bv = bias ? bias[n] : 0.f;
    for (int i=0;i<2;i++){
      int mbase = m0 + wm + i*16 + quad*4;
      for (int r=0;r<4;r++){
        float cv = acc[i][j][r] + bv;
        if (relu) cv = fmaxf(cv, 0.f);
        C[(size_t)(mbase+r)*N + n] = cv;
      }
    }
  }
}

// ---- attention: head-major qkv [BSQ][192]; block=(b,h); thread = 2 queries -
__global__ __launch_bounds__(256) void t11_attn(
    const float* __restrict__ qkv, const int* __restrict__ toks,
    float* __restrict__ aout){
  __shared__ float kb[SEQ][8];
  __shared__ float vb[SEQ][8];
  __shared__ float msk[SEQ];
  int bh = blockIdx.x;
  int b = bh >> 3, h = bh & 7;
  int tid = threadIdx.x;
  for (int idx = tid; idx < SEQ*2; idx += 256){
    int r = idx >> 1, half = (idx & 1)*4;
    const float* src = qkv + (size_t)(b*SEQ+r)*192 + h*8 + half;
    *(float4*)&kb[r][half] = *(const float4*)(src + 64);
    *(float4*)&vb[r][half] = *(const float4*)(src + 128);
  }
  for (int s2 = tid; s2 < SEQ; s2 += 256)
    msk[s2] = (toks[b*SEQ+s2]==0) ? -1e9f : 0.f;
  __syncthreads();
  const float scale = 0.057735026918962574f;  // 1/sqrt(300)
  float q0[8], q1[8];
  {
    const float* s0 = qkv + (size_t)(b*SEQ+tid)*192 + h*8;
    const float* s1 = qkv + (size_t)(b*SEQ+tid+256)*192 + h*8;
    *(float4*)&q0[0] = *(const float4*)s0; *(float4*)&q0[4] = *(const float4*)(s0+4);
    *(float4*)&q1[0] = *(const float4*)s1; *(float4*)&q1[4] = *(const float4*)(s1+4);
  }
  float sum0=0.f, sum1=0.f, o0[8]={}, o1[8]={};
  for (int k=0; k<SEQ; k++){
    float kr[8], vr[8];
    *(float4*)&kr[0] = *(float4*)&kb[k][0]; *(float4*)&kr[4] = *(float4*)&kb[k][4];
    *(float4*)&vr[0] = *(float4*)&vb[k][0]; *(float4*)&vr[4] = *(float4*)&vb[k][4];
    float s0v=0.f, s1v=0.f;
    for (int d=0; d<8; d++){ s0v = fmaf(q0[d],kr[d],s0v); s1v = fmaf(q1[d],kr[d],s1v); }
    float m = msk[k];
    float p0 = __expf(fminf(fmaf(s0v,scale,m), 60.f));   // masked: ~-1e9 -> exp = 0
    float p1 = __expf(fminf(fmaf(s1v,scale,m), 60.f));
    sum0 += p0; sum1 += p1;
    for (int d=0; d<8; d++){ o0[d] = fmaf(p0,vr[d],o0[d]); o1[d] = fmaf(p1,vr[d],o1[d]); }
  }
  float i0 = 1.f/sum0, i1 = 1.f/sum1;
  float* d0 = aout + (size_t)(b*SEQ+tid)*HD + h*8;      // head-major output
  float* d1 = aout + (size_t)(b*SEQ+tid+256)*HD + h*8;
  float r0[8], r1[8];
  for (int d=0;d<8;d++){ r0[d]=o0[d]*i0; r1[d]=o1[d]*i1; }
  *(float4*)d0 = *(float4*)&r0[0]; *(float4*)(d0+4) = *(float4*)&r0[4];
  *(float4*)d1 = *(float4*)&r1[0]; *(float4*)(d1+4) = *(float4*)&r1[4];
}

// ---------------- fused residual add + LayerNorm (ddof=1), optional acc+= ---
__global__ __launch_bounds__(256) void t10_addnorm(
                 const float* __restrict__ xa, const float* __restrict__ xb,
                 float* __restrict__ y, float* __restrict__ accum,
                 const float* __restrict__ gamma, const float* __restrict__ beta,
                 int l){
  __shared__ float red[8];
  int row = blockIdx.x, tid = threadIdx.x;
  size_t base = (size_t)row*HIDD;
  float v0 = xa[base+tid] + xb[base+tid];
  float v1 = 0.f;
  int has1 = (tid+256 < HIDD);
  if (has1) v1 = xa[base+tid+256] + xb[base+tid+256];
  float s = v0+v1, sq = v0*v0+v1*v1;
  for (int off=32; off; off>>=1){ s += __shfl_down(s,off); sq += __shfl_down(sq,off); }
  int lane = tid & 63, w = tid >> 6;
  if (lane==0){ red[w]=s; red[4+w]=sq; }
  __syncthreads();
  float sum = red[0]+red[1]+red[2]+red[3];
  float ssq = red[4]+red[5]+red[6]+red[7];
  float mu  = sum * (1.0f/HIDD);
  float var = (ssq - (float)HIDD*mu*mu) * (1.0f/(HIDD-1));
  float rstd = rsqrtf(var + 1e-8f);
  float g = gamma[l], be = beta[l];
  float o0 = g*(v0-mu)*rstd + be;
  y[base+tid] = o0;
  if (accum) accum[base+tid] += o0;
  if (has1){
    float o1 = g*(v1-mu)*rstd + be;
    y[base+tid+256] = o1;
    if (accum) accum[base+tid+256] += o1;
  }
}

// ---------------- fp32 tiled GEMM (classifier only, M=32) -------------------
#define GBM 64
#define GBN 64
#define GBK 16
__global__ __launch_bounds__(256) void t9_gemm(
                 const float* __restrict__ A, const float* __restrict__ W,
                 const float* __restrict__ bias, float* __restrict__ C,
                 int M, int N, int K, int relu){
  __shared__ float sA[GBM][GBK+1];
  __shared__ float sW[GBK][GBN];
  int tid = threadIdx.x;
  int tx = tid & 15, ty = tid >> 4;
  int m0 = blockIdx.y * GBM, n0 = blockIdx.x * GBN;
  float cacc[4][4] = {};
  int lr = tid >> 4, lk = tid & 15;
  int lc = tid & 63, lkb = tid >> 6;
  for (int k0 = 0; k0 < K; k0 += GBK){
    for (int t = 0; t < 4; t++){
      int row = lr + t*16;
      float vv = 0.f;
      int gm = m0 + row, gk = k0 + lk;
      if (gm < M && gk < K) vv = A[(size_t)gm*K + gk];
      sA[row][lk] = vv;
    }
    for (int t = 0; t < 4; t++){
      int kk = lkb + t*4;
      float vv = 0.f;
      int gk = k0 + kk, gn = n0 + lc;
      if (gk < K && gn < N) vv = W[(size_t)gk*N + gn];
      sW[kk][lc] = vv;
    }
    __syncthreads();
    for (int kk = 0; kk < GBK; kk++){
      float a0[4], b0[4];
      for (int i=0;i<4;i++) a0[i] = sA[ty*4+i][kk];
      for (int j=0;j<4;j++) b0[j] = sW[kk][tx*4+j];
      for (int i=0;i<4;i++)
        for (int j=0;j<4;j++)
          cacc[i][j] = fmaf(a0[i], b0[j], cacc[i][j]);
    }
    __syncthreads();
  }
  for (int i=0;i<4;i++){
    int m = m0 + ty*4 + i;
    if (m >= M) continue;
    for (int j=0;j<4;j++){
      int n = n0 + tx*4 + j;
      if (n >= N) continue;
      float cv = cacc[i][j];
      if (bias) cv += bias[n];
      if (relu) cv = fmaxf(cv, 0.f);
      C[(size_t)m*N + n] = cv;
    }
  }
}

// ---------------- sum over sequence: (B,S,HID) -> (B,HID) -------------------
__global__ void t10_colsum(const float* __restrict__ outb, float* __restrict__ sums){
  int b = blockIdx.x, j = threadIdx.x;
  if (j >= HIDD) return;
  float s = 0.f;
  size_t base = (size_t)b*SEQ*HIDD;
  for (int t=0; t<SEQ; t++) s += outb[base + (size_t)t*HIDD + j];
  sums[b*HIDD + j] = s;
}

// ---------------- classifier head: LayerNorm(ddof=1) + softmax -> fp32 -----
__device__ __forceinline__ float t10_bsum(float val, float* red){
  for (int off=32; off; off>>=1) val += __shfl_down(val, off);
  __syncthreads();
  if ((threadIdx.x & 63)==0) red[threadIdx.x>>6] = val;
  __syncthreads();
  return red[0]+red[1]+red[2]+red[3];
}
__device__ __forceinline__ float t10_bmax(float val, float* red){
  for (int off=32; off; off>>=1) val = fmaxf(val, __shfl_down(val, off));
  __syncthreads();
  if ((threadIdx.x & 63)==0) red[threadIdx.x>>6] = val;
  __syncthreads();
  return fmaxf(fmaxf(red[0],red[1]), fmaxf(red[2],red[3]));
}

__global__ __launch_bounds__(256) void t10_final(
                  const float* __restrict__ logits,
                  const float* __restrict__ gf, const float* __restrict__ bff,
                  float* __restrict__ outp){
  __shared__ float red[4];
  int b = blockIdx.x, tid = threadIdx.x;
  size_t base = (size_t)b*NCLS;
  float v[4];
  float s = 0.f, sq = 0.f;
  for (int t=0;t<4;t++){
    int j = tid + t*256;
    float x = (j < NCLS) ? logits[base+j] : 0.f;
    v[t] = x; s += x; sq += x*x;
  }
  s  = t10_bsum(s, red);
  sq = t10_bsum(sq, red);
  float mu  = s * (1.0f/NCLS);
  float var = (sq - (float)NCLS*mu*mu) * (1.0f/(NCLS-1));
  float rstd = rsqrtf(var + 1e-8f);
  float g = gf[0], be = bff[0];
  float y[4]; float mx = -1e30f;
  for (int t=0;t<4;t++){
    int j = tid + t*256;
    y[t] = g*(v[t]-mu)*rstd + be;
    if (j < NCLS) mx = fmaxf(mx, y[t]);
  }
  mx = t10_bmax(mx, red);
  float p[4]; float es = 0.f;
  for (int t=0;t<4;t++){
    int j = tid + t*256;
    p[t] = (j < NCLS) ? __expf(y[t]-mx) : 0.f;
    es += p[t];
  }
  es = t10_bsum(es, red);
  float inv = 1.0f/es;
  for (int t=0;t<4;t++){
    int j = tid + t*256;
    if (j < NCLS) outp[base+j] = p[t]*inv;
  }
}

// ---------------------------------------------------------------------------
extern "C" void kernel_launch(void* const* d_in, const int* in_sizes, int n_in,
                              void* d_out, int out_size, void* d_ws, size_t ws_size,
                              hipStream_t stream){
  const int*   toks = (const int*)d_in[0];
  const float* emb  = (const float*)d_in[1];
  const float* WQ   = (const float*)d_in[2];
  const float* WK   = (const float*)d_in[3];
  const float* WV   = (const float*)d_in[4];
  const float* WO   = (const float*)d_in[5];
  const float* W1   = (const float*)d_in[6];
  const float* b1   = (const float*)d_in[7];
  const float* W2   = (const float*)d_in[8];
  const float* b2   = (const float*)d_in[9];
  const float* g1   = (const float*)d_in[10];
  const float* be1  = (const float*)d_in[11];
  const float* g2   = (const float*)d_in[12];
  const float* be2  = (const float*)d_in[13];
  const float* Vd   = (const float*)d_in[14];
  const float* gf   = (const float*)d_in[15];
  const float* bff  = (const float*)d_in[16];
  float* outp = (float*)d_out;

  float* acc  = (float*)d_ws;
  float* xn   = acc  + (size_t)BSQ*HIDD;
  float* outb = xn   + (size_t)BSQ*HIDD;
  float* tmp  = outb + (size_t)BSQ*HIDD;
  float* big  = tmp  + (size_t)BSQ*HIDD;
  float* qkv  = big;                                // (BSQ,192) head-major
  float* aat  = big + (size_t)BSQ*192;              // (BSQ,64) head-major
  float* ff1  = big;                                // (BSQ,1200) reuse
  float* sums   = big + (size_t)BSQ*FFD;
  float* logits = sums + BATCH*HIDD;
  short* wt   = (short*)(logits + BATCH*NCLS);
  short* wqkv = wt;                                  // [6][192][320]
  short* wo   = wqkv + (size_t)6*192*320;            // [6][320][64]
  short* w1t  = wo   + (size_t)6*320*64;             // [6][1216][320]
  short* w2t  = w1t  + (size_t)6*1216*320;           // [6][320][1216]

  {
    int tq = 6*64*320;
    prep_w<<<(tq+255)/256,256,0,stream>>>(WQ, wqkv, 300, 64, 320, 64, 0,   19200, 61440, tq, 1);
    prep_w<<<(tq+255)/256,256,0,stream>>>(WK, wqkv, 300, 64, 320, 64, 64,  19200, 61440, tq, 1);
    prep_w<<<(tq+255)/256,256,0,stream>>>(WV, wqkv, 300, 64, 320, 64, 128, 19200, 61440, tq, 1);
    int to = 6*320*64;
    prep_w<<<(to+255)/256,256,0,stream>>>(WO, wo, 64, 300, 64, 320, 0, 19200, 20480, to, 0);
    int t1 = 6*1216*320;
    prep_w<<<(t1+255)/256,256,0,stream>>>(W1, w1t, 300, 1200, 320, 1216, 0, 360000, 389120, t1, 0);
    int t2 = 6*320*1216;
    prep_w<<<(t2+255)/256,256,0,stream>>>(W2, w2t, 1200, 300, 1216, 320, 0, 360000, 389120, t2, 0);
  }

  t10_embed<<<(BSQ*HIDD+255)/256, 256, 0, stream>>>(toks, emb, acc);

  for (int l = 0; l < NLAYERS; l++){
    mm_bf16<<<dim3(3,256),256,0,stream>>>(acc, wqkv + (size_t)l*61440, nullptr, qkv,
                                          BSQ, 192, 300, 320, 0);
    t11_attn<<<BATCH*NHEAD, 256, 0, stream>>>(qkv, toks, aat);
    mm_bf16<<<dim3(5,256),256,0,stream>>>(aat, wo + (size_t)l*20480, nullptr, tmp,
                                          BSQ, 300, 64, 64, 0);
    t10_addnorm<<<BSQ,256,0,stream>>>(tmp, acc, xn, nullptr, g1, be1, l);
    mm_bf16<<<dim3(19,256),256,0,stream>>>(xn, w1t + (size_t)l*389120, b1 + (size_t)l*FFD, ff1,
                                           BSQ, 1200, 300, 320, 1);
    mm_bf16<<<dim3(5,256),256,0,stream>>>(ff1, w2t + (size_t)l*389120, b2 + (size_t)l*HIDD, tmp,
                                          BSQ, 300, 1200, 1216, 0);
    t10_addnorm<<<BSQ,256,0,stream>>>(tmp, xn, outb, acc, g2, be2, l);
  }

  t10_colsum<<<BATCH, 320, 0, stream>>>(outb, sums);
  t9_gemm<<<dim3((NCLS+GBN-1)/GBN, 1),256,0,stream>>>(sums, Vd, nullptr, logits, BATCH, NCLS, HIDD, 0);
  t10_final<<<BATCH, 256, 0, stream>>>(logits, gf, bff, outp);

  hipStreamCaptureStatus cs = hipStreamCaptureStatusNone;
  hipStreamIsCapturing(stream, &cs);
  if (cs == hipStreamCaptureStatusNone){
    hipError_t e_sync = hipStreamSynchronize(stream);
    float ho[4] = {-1,-1,-1,-1};
    hipMemcpy(ho, d_out, 16, hipMemcpyDeviceToHost);
    fprintf(stderr, "[t11] sync=%s out[0..3]=%g,%g,%g,%g\n",
            hipGetErrorString(e_sync), ho[0], ho[1], ho[2], ho[3]);
    fflush(stderr);
  }
}